// Round 17
// baseline (47.747 us; speedup 1.0000x reference)
//
#include <hip/hip_runtime.h>
#include <math.h>

#define NBATCH 128
#define NP 256
#define NC 64
#define KNN 16
#define EPSV 1e-3f

typedef __bf16 bf16_t;
typedef bf16_t bf16x8 __attribute__((ext_vector_type(8)));
typedef float f32x4 __attribute__((ext_vector_type(4)));

static __device__ __forceinline__ f32x4 mfma16(bf16x8 a, bf16x8 b, f32x4 c) {
    return __builtin_amdgcn_mfma_f32_16x16x32_bf16(a, b, c, 0, 0, 0);
}
static __device__ __forceinline__ unsigned short f2bfu(float f) {
    union { bf16_t b; unsigned short u; } cv; cv.b = (bf16_t)f; return cv.u;
}
static __device__ __forceinline__ unsigned umin2(unsigned a, unsigned b) { return a < b ? a : b; }
static __device__ __forceinline__ unsigned umax2(unsigned a, unsigned b) { return a > b ? a : b; }

// relu'd f32x4 pair -> bf16x8 (j = (t&1)*4 + r ordering)
static __device__ __forceinline__ bf16x8 packrelu(f32x4 a, f32x4 b) {
    bf16x8 r;
    r[0] = (bf16_t)fmaxf(a[0], 0.f); r[1] = (bf16_t)fmaxf(a[1], 0.f);
    r[2] = (bf16_t)fmaxf(a[2], 0.f); r[3] = (bf16_t)fmaxf(a[3], 0.f);
    r[4] = (bf16_t)fmaxf(b[0], 0.f); r[5] = (bf16_t)fmaxf(b[1], 0.f);
    r[6] = (bf16_t)fmaxf(b[2], 0.f); r[7] = (bf16_t)fmaxf(b[3], 0.f);
    return r;
}

// 16-lane (i-group) sum via DPP butterfly: xor1, xor2 (quad_perm),
// half-mirror, mirror — pure VALU, no DS pipe, all lanes end with the sum.
template <int CTRL>
static __device__ __forceinline__ float dppadd(float v) {
    int x = __builtin_amdgcn_mov_dpp(__float_as_int(v), CTRL, 0xF, 0xF, true);
    return v + __int_as_float(x);
}
static __device__ __forceinline__ float sum16(float v) {
    v = dppadd<0xB1>(v);    // quad_perm [1,0,3,2]  (xor 1)
    v = dppadd<0x4E>(v);    // quad_perm [2,3,0,1]  (xor 2)
    v = dppadd<0x141>(v);   // row_half_mirror      (cross-quad in 8)
    v = dppadd<0x140>(v);   // row_mirror           (cross-half in 16)
    return v;
}

// Compiler-only ordering fence (R11-validated): wave-private LDS + in-order
// per-wave DS pipe -> no HW drain needed. Zero instructions.
#define CFENCE() asm volatile("" ::: "memory")

// Sorted-ascending insert, med3 form (2 ops/level, levels independent).
#define INSERTK(k_)                                                   \
    do {                                                              \
        _Pragma("unroll")                                             \
        for (int ii = KNN - 1; ii >= 1; --ii)                         \
            bk[ii] = umin2(umax2((k_), bk[ii - 1]), bk[ii]);          \
        bk[0] = umin2((k_), bk[0]);                                   \
    } while (0)

// ---------------------------------------------------------------------------
// setup_kernel: fused fcvt + prep + knn (one dispatch).
//   blocks [0,1024)    : fcvt  — features f32 -> bf16
//   blocks [1024,1106) : prep  — weight frags (swapped-operand A-frags) + BN
//                         (82 blocks: bnp needs e<384 — R16 only covered 255!)
//   blocks [1106,1362) : knn   — packed-key 2-way split kNN
//
// Swapped-operand scheme: D = W(A) · X(B). Weight-row permutation
// kappa(t,m) = (t>>1)*32 + (m>>2)*8 + (t&1)*4 + (m&3) makes the C-frag of
// layer L coincide with the B-frag of layer L+1 (register chaining, no LDS).
// scl folds into next layer's weights (scl>0 guaranteed); shf' = shf/scl
// becomes the MFMA C-input; final scl3/16 applied in the epilogue.
// wsf regions (u16), 8 frags each: V [0,4k) | w0hi [4k,8k) | scl1*w1 [8k,12k)
//   | scl2*w2 [12k,16k) | sc_w old-B-frags [16k,20k).
// bnp (f32): shf'[3][64] pos-order | scl3/16 [192,256) sem | sscl [256,320)
//   | sshf [320,384).
// ---------------------------------------------------------------------------
__global__ __launch_bounds__(256) void setup_kernel(
    const float* __restrict__ points, const float* __restrict__ features,
    const float* __restrict__ w0, const float* __restrict__ w1,
    const float* __restrict__ w2, const float* __restrict__ sc_w,
    const float* __restrict__ gammas, const float* __restrict__ betas,
    const float* __restrict__ means, const float* __restrict__ variances,
    const float* __restrict__ sc_gamma, const float* __restrict__ sc_beta,
    const float* __restrict__ sc_mean, const float* __restrict__ sc_var,
    unsigned short* __restrict__ fbf, unsigned short* __restrict__ wsf,
    float* __restrict__ bnp, int* __restrict__ knn_out)
{
    const int bid = blockIdx.x;
    if (bid < 1024) {
        // ---- fcvt section ----
        const int tid = bid * 256 + threadIdx.x;
        const float4 a = ((const float4*)features)[tid * 2];
        const float4 b = ((const float4*)features)[tid * 2 + 1];
        union { unsigned short s[8]; uint4 v; } r;
        r.s[0] = f2bfu(a.x); r.s[1] = f2bfu(a.y); r.s[2] = f2bfu(a.z); r.s[3] = f2bfu(a.w);
        r.s[4] = f2bfu(b.x); r.s[5] = f2bfu(b.y); r.s[6] = f2bfu(b.z); r.s[7] = f2bfu(b.w);
        ((uint4*)fbf)[tid] = r.v;
    } else if (bid < 1106) {
        // ---- prep section ----
        const int tid = (bid - 1024) * 256 + threadIdx.x;
        if (tid < 20480) {
            const int region = tid >> 12;          // 0:V 1:w0hi 2:w1' 3:w2' 4:ws
            const int e2 = tid & 4095;
            const int f = e2 >> 9;                 // frag = ks*4 + t
            const int r = e2 & 511;
            const int lane = r >> 3, j = r & 7;
            const int ks = f >> 2, t = f & 3;
            const int m = lane & 15;               // A-row (= D-row index)
            const int k_in = ks * 32 + (lane >> 4) * 8 + j;   // input channel
            const int kp = (t >> 1) * 32 + (m >> 2) * 8 + (t & 1) * 4 + (m & 3);
            float v;
            if (region == 0)      v = w0[k_in * 64 + kp] - w0[(64 + k_in) * 64 + kp];
            else if (region == 1) v = w0[(64 + k_in) * 64 + kp];
            else if (region == 2) {
                float s1 = gammas[k_in] * rsqrtf(variances[k_in] + EPSV);
                v = s1 * w1[k_in * 64 + kp];
            } else if (region == 3) {
                float s2 = gammas[64 + k_in] * rsqrtf(variances[64 + k_in] + EPSV);
                v = s2 * w2[k_in * 64 + kp];
            } else {
                v = sc_w[k_in * 64 + (4 * m + t)]; // old B-frag (epilogue)
            }
            wsf[tid] = f2bfu(v);
        } else {
            const int e = tid - 20480;
            if (e < 192) {
                const int L = e >> 6;
                const int pos = e & 63;
                const int t = pos >> 4, m = pos & 15;
                const int c = (t >> 1) * 32 + (m >> 2) * 8 + (t & 1) * 4 + (m & 3);
                float scl = gammas[L * 64 + c] * rsqrtf(variances[L * 64 + c] + EPSV);
                float shf = betas[L * 64 + c] - means[L * 64 + c] * scl;
                bnp[e] = shf / scl;
            } else if (e < 256) {
                const int c = e - 192;
                float s3 = gammas[128 + c] * rsqrtf(variances[128 + c] + EPSV);
                bnp[e] = s3 * (1.f / 16.f);
            } else if (e < 320) {
                const int c = e - 256;
                bnp[e] = sc_gamma[c] * rsqrtf(sc_var[c] + EPSV);
            } else if (e < 384) {
                const int c = e - 320;
                float s = sc_gamma[c] * rsqrtf(sc_var[c] + EPSV);
                bnp[e] = sc_beta[c] - sc_mean[c] * s;
            }
        }
    } else {
        // ---- knn section ----
        __shared__ __align__(16) float4 sp[NP];
        __shared__ unsigned sk[128][17];
        const int kb = bid - 1106;
        const int bb = kb >> 1;
        const int qbase = (kb & 1) * 128;
        const int t = threadIdx.x;
        const int qt = t & 127;
        const int half = t >> 7;
        const int p = qbase + qt;

        const float* pb = points + (size_t)bb * NP * 3;
        sp[t] = make_float4(pb[t * 3 + 0], pb[t * 3 + 1], pb[t * 3 + 2], 0.f);
        __syncthreads();

        const float4 qp = sp[p];
        unsigned bk[KNN];
#pragma unroll
        for (int i = 0; i < KNN; ++i) bk[i] = 0xFFFFFFFFu;

        const int cbase = half * 128;
#pragma unroll 4
        for (int c = 0; c < 128; ++c) {
            const int cand = cbase + c;
            const float4 P = sp[cand];
            const float dx = qp.x - P.x, dy = qp.y - P.y, dz = qp.z - P.z;
            const float d = fmaf(dx, dx, fmaf(dy, dy, dz * dz));
            unsigned key = (__float_as_uint(d) & 0xFFFFFF00u) | (unsigned)cand;
            key = (cand == p) ? 0xFFFFFFFFu : key;
            INSERTK(key);
        }

        if (half == 1) {
#pragma unroll
            for (int i = 0; i < KNN; ++i) sk[qt][i] = bk[i];
        }
        __syncthreads();
        if (half == 0) {
            for (int j = 0; j < KNN; ++j) {
                const unsigned key = sk[qt][j];
                if (key >= bk[KNN - 1]) break;
                INSERTK(key);
            }
            int* op = knn_out + ((size_t)bb * NP + p) * KNN;
#pragma unroll
            for (int i = 0; i < KNN; ++i) op[i] = (int)(bk[i] & 0xFFu);
        }
    }
}

// ---------------------------------------------------------------------------
// Edge MLP v11: swapped-operand register-chained MLP. Weights = A operand
// (LDS-shared, read per use), activations = B operand. C-frag(L) == B-frag
// (L+1) under the kappa permutation -> the 3-layer MLP runs entirely in
// registers: NO inter-layer LDS, NO fences in the main loop. Biases (shf')
// ride in the MFMA C-input; s0 (center term) precomputed per wave with the
// same orientation; k-mean via 4-stage DPP butterfly (VALU, no DS).
// LDS = 24K weights + 8K s0 + 8K fts = 40 KB -> 4 WG/CU = 16 waves/CU.
// ---------------------------------------------------------------------------
__global__ __launch_bounds__(256) void edge_kernel(
    const unsigned short* __restrict__ fbf, const int* __restrict__ knn_idx,
    const unsigned short* __restrict__ wsf, const float* __restrict__ bnp,
    float* __restrict__ out)
{
    __shared__ __align__(16) unsigned short wlds[24 * 512];   // 24 KB A-frags
    __shared__ __align__(16) float s0buf[4][8][64];           // 8 KB (pos-order)
    __shared__ __align__(16) float ftsbuf[4][8][64];          // 8 KB (sem-order)

    const int tid = threadIdx.x;
    const int wid = tid >> 6;
    const int l = tid & 63;
    const int i = l & 15;
    const int h = l >> 4;
    // bijective XCD swizzle: 1024 blocks = 8 XCDs x 128 contiguous work items
    const int wg = (blockIdx.x & 7) * 128 + (blockIdx.x >> 3);
    const int p0 = (wg * 4 + wid) * 8;
    const int b = p0 >> 8;

    // ---- cooperative load of W1/W2/W3 A-frags -> LDS (12288 u16) ----
    {
        const uint4* src = (const uint4*)(wsf + 4096);
        uint4* dst = (uint4*)wlds;
#pragma unroll
        for (int k = 0; k < 6; ++k) dst[tid + k * 256] = src[tid + k * 256];
    }
    #define WF(fi_) (*(const bf16x8*)&wlds[(fi_) * 512 + l * 8])

    // ---- bias C-inputs (position order: bnp[L*64 + t*16 + 4h + r]) ----
    f32x4 cin2[4], cin3[4];
#pragma unroll
    for (int t = 0; t < 4; ++t) {
        cin2[t] = *(const f32x4*)&bnp[64 + t * 16 + 4 * h];
        cin3[t] = *(const f32x4*)&bnp[128 + t * 16 + 4 * h];
    }

    // ---- prologue: s0 = shf1' + ctr @ V (V A-frags from global, one-shot) ----
    {
        const bf16x8* __restrict__ WV = (const bf16x8*)(wsf);
        const unsigned short* cp = fbf + (size_t)(p0 + (i & 7)) * NC;
        bf16x8 b0 = *(const bf16x8*)(cp + 8 * h);        // ch h*8+j   (k 0..31)
        bf16x8 b1 = *(const bf16x8*)(cp + 32 + 8 * h);   // ch 32+h*8+j
#pragma unroll
        for (int t = 0; t < 4; ++t) {
            f32x4 acc = *(const f32x4*)&bnp[t * 16 + 4 * h];   // shf1'
            acc = mfma16(WV[t * 64 + l], b0, acc);
            acc = mfma16(WV[(4 + t) * 64 + l], b1, acc);
            if (i < 8)
                *(f32x4*)&s0buf[wid][i][t * 16 + 4 * h] = acc;  // col=i=point
        }
    }
    int nks[8];
#pragma unroll
    for (int q = 0; q < 8; ++q) nks[q] = knn_idx[(size_t)(p0 + q) * KNN + i];

    __syncthreads();   // weights visible to all 4 waves (covers s0buf too)

    // prime point 0's neighbor B-fragments (lane i loads neighbor i)
    bf16x8 fb0, fb1;
    {
        const unsigned short* sp = fbf + (size_t)(b * NP + nks[0]) * NC;
        fb0 = *(const bf16x8*)(sp + 8 * h);
        fb1 = *(const bf16x8*)(sp + 32 + 8 * h);
    }

#pragma unroll
    for (int q = 0; q < 8; ++q) {
        f32x4 acc[4];
        // ---- L1: acc = (s0+shf1') + W1 . nbr ----
#pragma unroll
        for (int t = 0; t < 4; ++t) {
            f32x4 z = *(const f32x4*)&s0buf[wid][q][t * 16 + 4 * h];
            z = mfma16(WF(t), fb0, z);
            acc[t] = mfma16(WF(4 + t), fb1, z);
        }
        // prefetch next point's fragments (independent of MFMA chain)
        bf16x8 g0, g1;
        if (q < 7) {
            const unsigned short* sp = fbf + (size_t)(b * NP + nks[(q + 1) & 7]) * NC;
            g0 = *(const bf16x8*)(sp + 8 * h);
            g1 = *(const bf16x8*)(sp + 32 + 8 * h);
        }
        // relu + pack: C-frag == next B-frag (register chaining)
        bf16x8 x0 = packrelu(acc[0], acc[1]);
        bf16x8 x1 = packrelu(acc[2], acc[3]);

        // ---- L2 ----
#pragma unroll
        for (int t = 0; t < 4; ++t) {
            f32x4 z = mfma16(WF(8 + t), x0, cin2[t]);
            acc[t] = mfma16(WF(12 + t), x1, z);
        }
        bf16x8 y0 = packrelu(acc[0], acc[1]);
        bf16x8 y1 = packrelu(acc[2], acc[3]);

        // ---- L3 ----
#pragma unroll
        for (int t = 0; t < 4; ++t) {
            f32x4 z = mfma16(WF(16 + t), y0, cin3[t]);
            acc[t] = mfma16(WF(20 + t), y1, z);
        }
        // relu + sum over 16 neighbors (i-lanes) via DPP butterfly
        float st[4][4];
#pragma unroll
        for (int t = 0; t < 4; ++t)
#pragma unroll
            for (int r = 0; r < 4; ++r)
                st[t][r] = sum16(fmaxf(acc[t][r], 0.f));
        if (i == 0) {
#pragma unroll
            for (int t = 0; t < 4; ++t)
                *(float4*)&ftsbuf[wid][q][(t >> 1) * 32 + h * 8 + (t & 1) * 4] =
                    make_float4(st[t][0], st[t][1], st[t][2], st[t][3]);
        }
        fb0 = g0; fb1 = g1;
    }
    CFENCE();  // ftsbuf writes ordered before epilogue reads (same wave)

    // ---- shortcut GEMM + epilogue (old orientation, old permutation) ----
    {
        const bf16x8* __restrict__ WS = (const bf16x8*)(wsf + 16384);
        const int i4 = 4 * i;
        float4 sscl = *(const float4*)&bnp[256 + i4];
        float4 sshf = *(const float4*)&bnp[320 + i4];
        float4 f3q  = *(const float4*)&bnp[192 + i4];   // scl3/16, semantic
        const unsigned short* fp = fbf + (size_t)(p0 + (i & 7)) * NC;
        bf16x8 a0 = *(const bf16x8*)(fp + 8 * h);
        bf16x8 a1 = *(const bf16x8*)(fp + 32 + 8 * h);
        f32x4 acc[4];
#pragma unroll
        for (int t = 0; t < 4; ++t) {
            f32x4 z = {0.f, 0.f, 0.f, 0.f};
            z = mfma16(a0, WS[t * 64 + l], z);
            acc[t] = mfma16(a1, WS[(4 + t) * 64 + l], z);
        }
        if (h < 2) {
            const float* ss_ = (const float*)&sscl;
            const float* sf_ = (const float*)&sshf;
            const float* f3_ = (const float*)&f3q;
#pragma unroll
            for (int r = 0; r < 4; ++r) {
                const int q = h * 4 + r;
                float4 fts = *(const float4*)&ftsbuf[wid][q][i4];
                const float* ft_ = (const float*)&fts;
                float4 o;
                float* o_ = (float*)&o;
#pragma unroll
                for (int t = 0; t < 4; ++t)
                    o_[t] = fmaxf(fmaf(acc[t][r], ss_[t], sf_[t]) + ft_[t] * f3_[t], 0.f);
                *(float4*)&out[(size_t)(p0 + q) * NC + i4] = o;
            }
        }
    }
    #undef WF
}

extern "C" void kernel_launch(void* const* d_in, const int* in_sizes, int n_in,
                              void* d_out, int out_size, void* d_ws, size_t ws_size,
                              hipStream_t stream) {
    const float* points    = (const float*)d_in[0];
    const float* features  = (const float*)d_in[1];
    const float* w0        = (const float*)d_in[2];
    const float* w1        = (const float*)d_in[3];
    const float* w2        = (const float*)d_in[4];
    const float* gammas    = (const float*)d_in[5];
    const float* betas     = (const float*)d_in[6];
    const float* means     = (const float*)d_in[7];
    const float* variances = (const float*)d_in[8];
    const float* sc_w      = (const float*)d_in[9];
    const float* sc_gamma  = (const float*)d_in[10];
    const float* sc_beta   = (const float*)d_in[11];
    const float* sc_mean   = (const float*)d_in[12];
    const float* sc_var    = (const float*)d_in[13];
    float* out = (float*)d_out;

    int* knn_buf = (int*)d_ws;                                          // 2 MB
    unsigned short* fbf = (unsigned short*)((char*)d_ws + (1 << 21));   // 4 MB
    unsigned short* wsf = (unsigned short*)((char*)d_ws + (3 << 21));   // 40 KB
    float* bnp = (float*)((char*)d_ws + (3 << 21) + 40960);             // 1.5 KB

    setup_kernel<<<1362, 256, 0, stream>>>(points, features, w0, w1, w2, sc_w,
                                           gammas, betas, means, variances,
                                           sc_gamma, sc_beta, sc_mean, sc_var,
                                           fbf, wsf, bnp, knn_buf);
    edge_kernel<<<NBATCH * NP / 32, 256, 0, stream>>>(fbf, knn_buf, wsf, bnp, out);
}